// Round 4
// baseline (3219.928 us; speedup 1.0000x reference)
//
#include <hip/hip_runtime.h>
#include <stdint.h>
#include <math.h>

#define NN 50000
#define NE 800000

typedef __attribute__((ext_vector_type(8))) __bf16 bf16x8;
typedef __attribute__((ext_vector_type(8))) unsigned short u16x8;
typedef __attribute__((ext_vector_type(4))) float f32x4;
typedef unsigned int uint32;

// ---------------------------------------------------------------------------
// One-time CSR build: histogram -> exclusive scan -> scatter (src only).
// ---------------------------------------------------------------------------
__global__ void hist_k(const int* __restrict__ dst, int* __restrict__ hist) {
    int e = blockIdx.x * 256 + threadIdx.x;
    if (e < NE) atomicAdd(&hist[dst[e]], 1);
}

__global__ void scan_k(const int* __restrict__ hist, int* __restrict__ row_off) {
    __shared__ int lds[1024];
    const int tid = threadIdx.x;
    int carry = 0;
    for (int base = 0; base < NN; base += 1024) {
        int i = base + tid;
        int v = (i < NN) ? hist[i] : 0;
        lds[tid] = v;
        __syncthreads();
        #pragma unroll
        for (int s = 1; s < 1024; s <<= 1) {
            int add = (tid >= s) ? lds[tid - s] : 0;
            __syncthreads();
            lds[tid] += add;
            __syncthreads();
        }
        int incl = lds[tid];
        if (i < NN) row_off[i] = carry + incl - v;   // exclusive
        carry += lds[1023];
        __syncthreads();
    }
    if (tid == 0) row_off[NN] = carry;               // == NE
}

__global__ void copy_k(const int* __restrict__ a, int* __restrict__ b, int n) {
    int i = blockIdx.x * 256 + threadIdx.x;
    if (i < n) b[i] = a[i];
}

__global__ void scatter_k(const int* __restrict__ src, const int* __restrict__ dst,
                          int* __restrict__ cnt, int* __restrict__ s_src) {
    int e = blockIdx.x * 256 + threadIdx.x;
    if (e < NE) {
        int d = dst[e];
        int p = atomicAdd(&cnt[d], 1);
        s_src[p] = src[e];
    }
}

// ---------------------------------------------------------------------------
// Node transform: u = y @ (W1a - W1b) + b1 ; v = y @ W1b   (fp32 VALU)
// ---------------------------------------------------------------------------
template<int CIN, int COUT, bool FIRST>
__global__ void node_transform(const float* __restrict__ xin,
                               const float* __restrict__ ain,
                               const float* __restrict__ b2p,
                               const float* __restrict__ W1,
                               const float* __restrict__ b1,
                               float* __restrict__ U,
                               float* __restrict__ Vv)
{
    __shared__ float ylds[32][CIN];
    const int nbase = blockIdx.x * 32;
    const int tid = threadIdx.x;

    for (int idx = tid; idx < 32 * CIN; idx += COUT) {
        int nn = idx / CIN, k = idx - nn * CIN;
        int n = nbase + nn;
        float val = 0.f;
        if (n < NN) {
            if (FIRST) {
                val = xin[(size_t)n * CIN + k];
            } else {
                float a = ain[(size_t)n * CIN + k];
                val = fmaxf(a + b2p[k], 0.f);   // -inf sentinel -> 0
            }
        }
        ylds[nn][k] = val;
    }
    __syncthreads();

    const int j = tid;
    float ua[32], va[32];
    #pragma unroll
    for (int t = 0; t < 32; ++t) { ua[t] = 0.f; va[t] = 0.f; }

    for (int k4 = 0; k4 < CIN / 4; ++k4) {
        float wd[4], wb[4];
        #pragma unroll
        for (int i = 0; i < 4; ++i) {
            float a = W1[(size_t)(k4 * 4 + i) * COUT + j];
            float b = W1[(size_t)(CIN + k4 * 4 + i) * COUT + j];
            wb[i] = b;
            wd[i] = a - b;
        }
        #pragma unroll
        for (int t = 0; t < 32; ++t) {
            const float4 y4 = *reinterpret_cast<const float4*>(&ylds[t][k4 * 4]);
            ua[t] = fmaf(y4.x, wd[0], ua[t]);
            ua[t] = fmaf(y4.y, wd[1], ua[t]);
            ua[t] = fmaf(y4.z, wd[2], ua[t]);
            ua[t] = fmaf(y4.w, wd[3], ua[t]);
            va[t] = fmaf(y4.x, wb[0], va[t]);
            va[t] = fmaf(y4.y, wb[1], va[t]);
            va[t] = fmaf(y4.z, wb[2], va[t]);
            va[t] = fmaf(y4.w, wb[3], va[t]);
        }
    }

    const float bj = b1[j];
    for (int t = 0; t < 32; ++t) {
        int n = nbase + t;
        if (n < NN) {
            U [(size_t)n * COUT + j] = ua[t] + bj;
            Vv[(size_t)n * COUT + j] = va[t];
        }
    }
}

// ---------------------------------------------------------------------------
// W2 -> MFMA B-fragment prep (hi/lo bf16 split), fragment-packed layout.
// frag = nt*KS + ks; lane l holds W2[ks*32 + (l>>4)*8 + m][nt*16 + (l&15)],
// m=0..7, packed as 8 ushort (bf16 bits) at F[(frag*64+lane)*8].
// ---------------------------------------------------------------------------
template<int COUT>
__global__ void w2frag_prep(const float* __restrict__ W2,
                            unsigned short* __restrict__ Fhi,
                            unsigned short* __restrict__ Flo)
{
    constexpr int KS = COUT / 32;
    constexpr int NT = COUT / 16;
    int t = blockIdx.x * 256 + threadIdx.x;
    if (t >= NT * KS * 64) return;
    int frag = t >> 6, lane = t & 63;
    int ks = frag % KS, nt = frag / KS;
    int col = nt * 16 + (lane & 15);
    int k0 = ks * 32 + (lane >> 4) * 8;
    unsigned short h8[8], l8[8];
    #pragma unroll
    for (int m = 0; m < 8; ++m) {
        float w = W2[(size_t)(k0 + m) * COUT + col];
        __bf16 hb = (__bf16)w;
        float hf = (float)hb;
        __bf16 lb = (__bf16)(w - hf);
        h8[m] = __builtin_bit_cast(unsigned short, hb);
        l8[m] = __builtin_bit_cast(unsigned short, lb);
    }
    size_t base = (size_t)t * 8;
    #pragma unroll
    for (int m = 0; m < 8; ++m) { Fhi[base + m] = h8[m]; Flo[base + m] = l8[m]; }
}

// ---------------------------------------------------------------------------
// MFMA edge kernel. One wave per dst node; 16-edge passes.
//   t = relu(u[n] + v[src]) split to bf16 hi/lo in LDS (XOR granule swizzle);
//   h = t@W2 via 3-term split MFMA (hi*whi + hi*wlo + lo*whi), fp32 acc;
//   masked in-reg max + shfl reduce; direct store. No atomics, no barriers
//   in the per-node loop.
// B-hi fragments in VGPR (loaded once); B-lo fragments from LDS (frag-packed,
// conflict-free). Block = 512 (8 nodes).
// ---------------------------------------------------------------------------
static __device__ __forceinline__ void split_pack(float4 t4, uint2& hw, uint2& lw) {
    unsigned short h[4], l[4];
    float c[4] = {t4.x, t4.y, t4.z, t4.w};
    #pragma unroll
    for (int i = 0; i < 4; ++i) {
        __bf16 hb = (__bf16)c[i];
        float hf = (float)hb;
        __bf16 lb = (__bf16)(c[i] - hf);
        h[i] = __builtin_bit_cast(unsigned short, hb);
        l[i] = __builtin_bit_cast(unsigned short, lb);
    }
    hw.x = (uint32)h[0] | ((uint32)h[1] << 16);
    hw.y = (uint32)h[2] | ((uint32)h[3] << 16);
    lw.x = (uint32)l[0] | ((uint32)l[1] << 16);
    lw.y = (uint32)l[2] | ((uint32)l[3] << 16);
}

template<int COUT>
__global__ void __launch_bounds__(512, 2) edge_node_mfma(
    const float* __restrict__ U, const float* __restrict__ Vv,
    const int* __restrict__ s_src, const int* __restrict__ row_off,
    const unsigned short* __restrict__ Fhi, const unsigned short* __restrict__ Flo,
    float* __restrict__ agg)
{
    constexpr int KS = COUT / 32;          // MFMA K-steps
    constexpr int NT = COUT / 16;          // N tiles (output col blocks)
    constexpr int NFRAG = KS * NT;
    constexpr int CH = COUT / 4;           // float4 chunks per t row
    constexpr int EPR = 64 / CH;           // edges staged per round

    __shared__ unsigned short w2lo[NFRAG * 512];     // 1KB per frag
    __shared__ unsigned short thi[8][16 * COUT];
    __shared__ unsigned short tlo[8][16 * COUT];

    const int tid = threadIdx.x;
    // stage lo-fragments to LDS (block-wide, once)
    for (int i = tid; i < NFRAG * 64; i += 512)
        *reinterpret_cast<u16x8*>(&w2lo[i * 8]) =
            *reinterpret_cast<const u16x8*>(&Flo[(size_t)i * 8]);

    const int wave = tid >> 6, lane = tid & 63;

    // B-hi fragments -> registers (static-indexed; stays in VGPRs)
    bf16x8 bhi[NT][KS];
    #pragma unroll
    for (int nt = 0; nt < NT; ++nt)
        #pragma unroll
        for (int ks = 0; ks < KS; ++ks) {
            u16x8 raw = *reinterpret_cast<const u16x8*>(
                &Fhi[(size_t)((nt * KS + ks) * 64 + lane) * 8]);
            bhi[nt][ks] = __builtin_bit_cast(bf16x8, raw);
        }

    __syncthreads();   // w2lo ready; no block syncs after this

    const int n = blockIdx.x * 8 + wave;          // grid = NN/8 exactly
    const int off0 = row_off[n];
    const int deg  = row_off[n + 1] - off0;

    // staging role (fixed per lane): float4 chunk grp of edge e
    const int grp = lane & (CH - 1);
    const int e0s = lane / CH;
    const int gran = grp >> 1, half = grp & 1;    // 16B granule / 8B half

    const float4 u4 = *reinterpret_cast<const float4*>(&U[(size_t)n * COUT + grp * 4]);

    unsigned short* myhi = thi[wave];
    unsigned short* mylo = tlo[wave];

    const int arow = lane & 15;                   // A row (edge within tile)
    const int akc  = lane >> 4;                   // A k-chunk within K-step

    float nmax[NT];
    #pragma unroll
    for (int nt = 0; nt < NT; ++nt) nmax[nt] = -INFINITY;

    for (int pb = 0; pb < deg; pb += 16) {
        // ---- stage 16 x COUT tile as swizzled bf16 hi/lo ----
        #pragma unroll
        for (int r = 0; r < 16 / EPR; ++r) {
            const int e = r * EPR + e0s;
            float4 t4 = {0.f, 0.f, 0.f, 0.f};
            const int ge = pb + e;
            if (ge < deg) {
                int sv = s_src[off0 + ge];
                float4 v4 = *reinterpret_cast<const float4*>(
                    &Vv[(size_t)sv * COUT + grp * 4]);
                t4.x = fmaxf(u4.x + v4.x, 0.f);
                t4.y = fmaxf(u4.y + v4.y, 0.f);
                t4.z = fmaxf(u4.z + v4.z, 0.f);
                t4.w = fmaxf(u4.w + v4.w, 0.f);
            }
            uint2 hw, lw;
            split_pack(t4, hw, lw);
            const int woff = e * COUT + ((gran ^ (e & 7)) << 3) + (half << 2);
            *reinterpret_cast<uint2*>(&myhi[woff]) = hw;
            *reinterpret_cast<uint2*>(&mylo[woff]) = lw;
        }
        // (same-wave ds_write -> ds_read on same arrays: compiler orders)

        // ---- 3-term split MFMA GEMM: [16 x COUT] @ [COUT x COUT] ----
        f32x4 acc[NT];
        #pragma unroll
        for (int nt = 0; nt < NT; ++nt) acc[nt] = f32x4{0.f, 0.f, 0.f, 0.f};

        #pragma unroll
        for (int ks = 0; ks < KS; ++ks) {
            const int g = ks * 4 + akc;
            const int aoff = arow * COUT + ((g ^ (arow & 7)) << 3);
            bf16x8 ahi = __builtin_bit_cast(bf16x8,
                *reinterpret_cast<const u16x8*>(&myhi[aoff]));
            bf16x8 alo = __builtin_bit_cast(bf16x8,
                *reinterpret_cast<const u16x8*>(&mylo[aoff]));
            #pragma unroll
            for (int nt = 0; nt < NT; ++nt) {
                bf16x8 blo = __builtin_bit_cast(bf16x8,
                    *reinterpret_cast<const u16x8*>(
                        &w2lo[(size_t)((nt * KS + ks) * 64 + lane) * 8]));
                acc[nt] = __builtin_amdgcn_mfma_f32_16x16x32_bf16(
                              ahi, bhi[nt][ks], acc[nt], 0, 0, 0);
                acc[nt] = __builtin_amdgcn_mfma_f32_16x16x32_bf16(
                              ahi, blo, acc[nt], 0, 0, 0);
                acc[nt] = __builtin_amdgcn_mfma_f32_16x16x32_bf16(
                              alo, bhi[nt][ks], acc[nt], 0, 0, 0);
            }
        }

        // ---- masked max over this pass's 16 edges ----
        // D layout: row (edge) = (lane>>4)*4 + r, col = nt*16 + (lane&15)
        #pragma unroll
        for (int nt = 0; nt < NT; ++nt) {
            float m4 = -INFINITY;
            #pragma unroll
            for (int r = 0; r < 4; ++r) {
                int e = akc * 4 + r;
                if (pb + e < deg) m4 = fmaxf(m4, acc[nt][r]);
            }
            m4 = fmaxf(m4, __shfl_xor(m4, 16, 64));
            m4 = fmaxf(m4, __shfl_xor(m4, 32, 64));
            nmax[nt] = fmaxf(nmax[nt], m4);
        }
    }

    // ---- direct store; deg==0 leaves -inf sentinel ----
    if (lane < 16) {
        #pragma unroll
        for (int nt = 0; nt < NT; ++nt)
            agg[(size_t)n * COUT + nt * 16 + lane] = nmax[nt];
    }
}

__global__ void finalize_k(const float* __restrict__ agg,
                           const float* __restrict__ b2,
                           float* __restrict__ out) {
    int i = blockIdx.x * 256 + threadIdx.x;
    if (i < NN * 128) {
        float a = agg[i];
        out[i] = (a == -INFINITY) ? 0.f : a + b2[i & 127];
    }
}

// ---------------------------------------------------------------------------
extern "C" void kernel_launch(void* const* d_in, const int* in_sizes, int n_in,
                              void* d_out, int out_size, void* d_ws, size_t ws_size,
                              hipStream_t stream)
{
    const float* x  = (const float*)d_in[0];
    const int*   ei = (const int*)d_in[1];
    const int* src = ei;          // edge_index[0]
    const int* dst = ei + NE;     // edge_index[1]

    const float *W1[4], *B1[4], *W2[4], *B2[4];
    for (int i = 0; i < 4; ++i) {
        W1[i] = (const float*)d_in[2 + 4 * i];
        B1[i] = (const float*)d_in[3 + 4 * i];
        W2[i] = (const float*)d_in[4 + 4 * i];
        B2[i] = (const float*)d_in[5 + 4 * i];
    }

    float* U   = (float*)d_ws;
    float* V   = U   + (size_t)NN * 128;
    float* agg = V   + (size_t)NN * 128;
    int* row_off = (int*)(agg + (size_t)NN * 128);   // NN+16 ints (padded)
    int* cnt     = row_off + (NN + 16);              // NN+16 ints
    int* s_src   = cnt + (NN + 16);                  // NE ints
    unsigned short* fbase = (unsigned short*)(s_src + NE);
    // per layer: 16384 ushorts hi + 16384 lo (layer0 uses first 4096 of each)
    unsigned short *FH[4], *FL[4];
    for (int i = 0; i < 4; ++i) {
        FH[i] = fbase + (size_t)i * 32768;
        FL[i] = FH[i] + 16384;
    }

    float* out = (float*)d_out;

    // ---- one-time CSR build ----
    (void)hipMemsetAsync(cnt, 0, (size_t)NN * sizeof(int), stream);
    hipLaunchKernelGGL(hist_k, dim3((NE + 255) / 256), dim3(256), 0, stream, dst, cnt);
    hipLaunchKernelGGL(scan_k, dim3(1), dim3(1024), 0, stream, cnt, row_off);
    hipLaunchKernelGGL(copy_k, dim3((NN + 255) / 256), dim3(256), 0, stream, row_off, cnt, NN);
    hipLaunchKernelGGL(scatter_k, dim3((NE + 255) / 256), dim3(256), 0, stream, src, dst, cnt, s_src);

    // ---- W2 fragment prep (hi/lo bf16 split), all 4 layers ----
    hipLaunchKernelGGL((w2frag_prep<64>),  dim3(2), dim3(256), 0, stream, W2[0], FH[0], FL[0]);
    hipLaunchKernelGGL((w2frag_prep<128>), dim3(8), dim3(256), 0, stream, W2[1], FH[1], FL[1]);
    hipLaunchKernelGGL((w2frag_prep<128>), dim3(8), dim3(256), 0, stream, W2[2], FH[2], FL[2]);
    hipLaunchKernelGGL((w2frag_prep<128>), dim3(8), dim3(256), 0, stream, W2[3], FH[3], FL[3]);

    const int nblkA = (NN + 31) / 32;
    const int nblkE = NN / 8;      // 6250

    // ---- layer 0: 32 -> 64 ----
    hipLaunchKernelGGL((node_transform<32, 64, true>), dim3(nblkA), dim3(64), 0, stream,
                       x, nullptr, nullptr, W1[0], B1[0], U, V);
    hipLaunchKernelGGL((edge_node_mfma<64>), dim3(nblkE), dim3(512), 0, stream,
                       U, V, s_src, row_off, FH[0], FL[0], agg);

    // ---- layer 1: 64 -> 128 ----
    hipLaunchKernelGGL((node_transform<64, 128, false>), dim3(nblkA), dim3(128), 0, stream,
                       nullptr, agg, B2[0], W1[1], B1[1], U, V);
    hipLaunchKernelGGL((edge_node_mfma<128>), dim3(nblkE), dim3(512), 0, stream,
                       U, V, s_src, row_off, FH[1], FL[1], agg);

    // ---- layer 2: 128 -> 128 ----
    hipLaunchKernelGGL((node_transform<128, 128, false>), dim3(nblkA), dim3(128), 0, stream,
                       nullptr, agg, B2[1], W1[2], B1[2], U, V);
    hipLaunchKernelGGL((edge_node_mfma<128>), dim3(nblkE), dim3(512), 0, stream,
                       U, V, s_src, row_off, FH[2], FL[2], agg);

    // ---- layer 3: 128 -> 128 ----
    hipLaunchKernelGGL((node_transform<128, 128, false>), dim3(nblkA), dim3(128), 0, stream,
                       nullptr, agg, B2[2], W1[3], B1[3], U, V);
    hipLaunchKernelGGL((edge_node_mfma<128>), dim3(nblkE), dim3(512), 0, stream,
                       U, V, s_src, row_off, FH[3], FL[3], agg);

    // ---- finalize: +b2_3, empty -> 0 ----
    hipLaunchKernelGGL(finalize_k, dim3((NN * 128 + 255) / 256), dim3(256), 0, stream,
                       agg, B2[3], out);
}